// Round 3
// baseline (233.648 us; speedup 1.0000x reference)
//
#include <hip/hip_runtime.h>
#include <hip/hip_bf16.h>

#define NROW 50000
#define DIN 128
#define DM 256
#define HH 4
#define NC 40
#define BHN 200000
#define NBLK 782   // ceil(50000/64)

typedef float f32x4 __attribute__((ext_vector_type(4)));
typedef short bf16x8 __attribute__((ext_vector_type(8)));

__device__ __forceinline__ unsigned short f2bf(float x) {
    unsigned int u = __float_as_uint(x);
    u += 0x7fffu + ((u >> 16) & 1u);
    return (unsigned short)(u >> 16);
}

__device__ __forceinline__ unsigned int pk2(float lo, float hi) {
    __hip_bfloat162 h = __float22bfloat162_rn(make_float2(lo, hi));
    return *(unsigned int*)&h;
}

// -------- prep: scatter vcol + build bf16 Wt / Wgtp / bias2, one launch --------
__global__ __launch_bounds__(256) void k_prep(const int* __restrict__ pi,
                                              const float* __restrict__ pv,
                                              const float* __restrict__ Win,
                                              const float* __restrict__ Wh,
                                              const float* __restrict__ gamma,
                                              const float* __restrict__ beta,
                                              const float* __restrict__ bh,
                                              float* __restrict__ vcol,
                                              unsigned short* __restrict__ Wt,
                                              unsigned short* __restrict__ Wgtp,
                                              float* __restrict__ bias2) {
    const int bid = blockIdx.x, tid = threadIdx.x;
    if (bid < 782) {                      // scatter: vcol[h][col] = v
        int k = bid * 256 + tid;
        if (k < BHN) {
            int b   = pi[k];
            int col = pi[2 * BHN + k];
            vcol[b * NROW + col] = pv[k];
        }
    } else if (bid == 782) {              // Wgtp[c][d] = bf16(gamma[d]*Wh[d][c]), c<48 zero-padded
        #pragma unroll 4
        for (int q = 0; q < 192; ++q) {
            int e = q * 256 + tid;
            int c = e >> 10, d = e & 1023;
            Wgtp[c * 1024 + d] = (c < NC) ? f2bf(gamma[d] * Wh[d * NC + c]) : (unsigned short)0;
        }
    } else if (bid == 783) {              // bias2[c] = bh[c] + sum_d beta[d]*Wh[d][c]
        if (tid < NC) {
            float a = bh[tid];
            #pragma unroll 8
            for (int d = 0; d < 1024; ++d) a = fmaf(beta[d], Wh[d * NC + tid], a);
            bias2[tid] = a;
        }
    } else {                              // 784..799: Wt[n][k] = bf16(Win[k][n])
        int base = (bid - 784) * 4096;
        #pragma unroll 4
        for (int q = 0; q < 16; ++q) {
            int e = base + q * 256 + tid;
            int n = e >> 8, k = e & 255;
            Wt[n * DM + k] = f2bf(Win[k * DM + n]);
        }
    }
}

// -------- fused: G = A@W_in (regs) -> LN stats -> per-head z (wave-private LDS) -> head MFMA --------
__global__ __launch_bounds__(256, 2) void k_fused(
    const float* __restrict__ feats, const float* __restrict__ appd,
    const unsigned short* __restrict__ Wt,   // [256 n][256 k] bf16
    const unsigned short* __restrict__ Wgtp, // [48 c][1024 d] bf16, gamma folded, zero-padded
    const float* __restrict__ vcol,          // [4][NROW]
    const float* __restrict__ b_in,          // [256]
    const float* __restrict__ bias2,         // [40]
    float* __restrict__ out)                 // [NROW][40]
{
    __shared__ __align__(16) unsigned short zbuf[4][64 * 72]; // per-wave z slice [64 rows][72]
    __shared__ float sred[2][64][4];                          // stats partials [s/ss][row][wave]
    __shared__ float vsL[HH][64];

    const int tid = threadIdx.x;
    const int wv = tid >> 6;
    const int ln = tid & 63;
    const int quad = ln >> 4;
    const int lr = ln & 15;
    const int j0 = blockIdx.x * 64;
    const int colbase = wv * 64;

    if (tid < 64) {
        int j = min(j0 + tid, NROW - 1);
        #pragma unroll
        for (int h = 0; h < HH; ++h) vsL[h][tid] = vcol[h * NROW + j];
    }
    __syncthreads();

    float bt[4];
    #pragma unroll
    for (int t = 0; t < 4; ++t) bt[t] = b_in[colbase + t * 16 + lr];
    float b2[3];
    #pragma unroll
    for (int t = 0; t < 3; ++t) {
        int c = t * 16 + lr;
        b2[t] = (c < NC) ? bias2[c] : 0.f;
    }

    // ---- phase 1: accG[rt][t] = G[64 rows][wave's 64 cols], no LDS, no barriers ----
    int ar[4];
    #pragma unroll
    for (int rt = 0; rt < 4; ++rt) ar[rt] = min(j0 + rt * 16 + lr, NROW - 1);

    const f32x4 zero4 = {0.f, 0.f, 0.f, 0.f};
    f32x4 accG[4][4];
    #pragma unroll
    for (int rt = 0; rt < 4; ++rt)
        #pragma unroll
        for (int t = 0; t < 4; ++t) accG[rt][t] = zero4;

    for (int kc = 0; kc < 8; ++kc) {
        const float* src = (kc < 4) ? feats : appd;
        const int ko = (kc & 3) * 32 + quad * 8;
        bf16x8 af[4];
        #pragma unroll
        for (int rt = 0; rt < 4; ++rt) {
            float4 x0 = *(const float4*)&src[(size_t)ar[rt] * DIN + ko];
            float4 x1 = *(const float4*)&src[(size_t)ar[rt] * DIN + ko + 4];
            union { unsigned int ui[4]; bf16x8 v; } u;
            u.ui[0] = pk2(x0.x, x0.y);
            u.ui[1] = pk2(x0.z, x0.w);
            u.ui[2] = pk2(x1.x, x1.y);
            u.ui[3] = pk2(x1.z, x1.w);
            af[rt] = u.v;
        }
        #pragma unroll
        for (int t = 0; t < 4; ++t) {
            bf16x8 bf = *(const bf16x8*)&Wt[(size_t)(colbase + t * 16 + lr) * DM + kc * 32 + quad * 8];
            #pragma unroll
            for (int rt = 0; rt < 4; ++rt)
                accG[rt][t] = __builtin_amdgcn_mfma_f32_16x16x32_bf16(af[rt], bf, accG[rt][t], 0, 0, 0);
        }
    }

    // ---- phase 2: LN stats (partial over wave's 64 cols x 4 heads, then cross-wave) ----
    float s[4][4] = {}, ss[4][4] = {};
    for (int h = 0; h < HH; ++h) {
        #pragma unroll
        for (int rt = 0; rt < 4; ++rt)
            #pragma unroll
            for (int rg = 0; rg < 4; ++rg) {
                float v = vsL[h][rt * 16 + quad * 4 + rg];
                #pragma unroll
                for (int t = 0; t < 4; ++t) {
                    float y = v * fmaxf(fmaf(v, accG[rt][t][rg], bt[t]), 0.f);
                    s[rt][rg] += y;
                    ss[rt][rg] = fmaf(y, y, ss[rt][rg]);
                }
            }
    }
    #pragma unroll
    for (int m = 1; m <= 8; m <<= 1)
        #pragma unroll
        for (int rt = 0; rt < 4; ++rt)
            #pragma unroll
            for (int rg = 0; rg < 4; ++rg) {
                s[rt][rg] += __shfl_xor(s[rt][rg], m);
                ss[rt][rg] += __shfl_xor(ss[rt][rg], m);
            }
    if (lr == 0) {
        #pragma unroll
        for (int rt = 0; rt < 4; ++rt)
            #pragma unroll
            for (int rg = 0; rg < 4; ++rg) {
                int r = rt * 16 + quad * 4 + rg;
                sred[0][r][wv] = s[rt][rg];
                sred[1][r][wv] = ss[rt][rg];
            }
    }
    __syncthreads();
    float rs[4][4], nm[4][4];
    #pragma unroll
    for (int rt = 0; rt < 4; ++rt)
        #pragma unroll
        for (int rg = 0; rg < 4; ++rg) {
            int r = rt * 16 + quad * 4 + rg;
            f32x4 s4 = *(const f32x4*)&sred[0][r][0];
            f32x4 q4 = *(const f32x4*)&sred[1][r][0];
            float S = (s4.x + s4.y) + (s4.z + s4.w);
            float Q = (q4.x + q4.y) + (q4.z + q4.w);
            float mm = S * (1.f / 1024.f);
            float var = Q * (1.f / 1024.f) - mm * mm;
            float r_ = rsqrtf(var + 1e-5f);
            rs[rt][rg] = r_;
            nm[rt][rg] = -mm * r_;
        }

    // ---- phase 3: per head, write z slice (own buf), barrier, MFMA full-K for 16 rows ----
    f32x4 accO[3];
    #pragma unroll
    for (int t = 0; t < 3; ++t) accO[t] = zero4;
    unsigned short* zb = zbuf[wv];

    for (int h = 0; h < HH; ++h) {
        if (h) __syncthreads();   // protect prev head's reads from this head's writes
        #pragma unroll
        for (int rt = 0; rt < 4; ++rt)
            #pragma unroll
            for (int rg = 0; rg < 4; ++rg) {
                float v = vsL[h][rt * 16 + quad * 4 + rg];
                float r_ = rs[rt][rg], n_ = nm[rt][rg];
                #pragma unroll
                for (int t = 0; t < 4; ++t) {
                    float y = v * fmaxf(fmaf(v, accG[rt][t][rg], bt[t]), 0.f);
                    float z = fmaf(y, r_, n_);
                    zb[(rt * 16 + quad * 4 + rg) * 72 + t * 16 + lr] = f2bf(z);
                }
            }
        __syncthreads();
        #pragma unroll
        for (int kc = 0; kc < 8; ++kc) {
            bf16x8 af = *(const bf16x8*)&zbuf[kc >> 1][(wv * 16 + lr) * 72 + (kc & 1) * 32 + quad * 8];
            #pragma unroll
            for (int t = 0; t < 3; ++t) {
                bf16x8 bf = *(const bf16x8*)&Wgtp[(size_t)(t * 16 + lr) * 1024 + h * 256 + kc * 32 + quad * 8];
                accO[t] = __builtin_amdgcn_mfma_f32_16x16x32_bf16(af, bf, accO[t], 0, 0, 0);
            }
        }
    }

    // ---- store: wave wv owns rows wv*16..wv*16+15 ----
    #pragma unroll
    for (int t = 0; t < 3; ++t)
        #pragma unroll
        for (int rg = 0; rg < 4; ++rg) {
            int row = j0 + wv * 16 + quad * 4 + rg;
            int c = t * 16 + lr;
            if (row < NROW && c < NC)
                out[(size_t)row * NC + c] = accO[t][rg] + b2[t];
        }
}

extern "C" void kernel_launch(void* const* d_in, const int* in_sizes, int n_in,
                              void* d_out, int out_size, void* d_ws, size_t ws_size,
                              hipStream_t stream) {
    const int*   pi    = (const int*)d_in[0];
    const float* pv    = (const float*)d_in[1];
    const float* feats = (const float*)d_in[2];
    const float* appd  = (const float*)d_in[3];
    const float* Win   = (const float*)d_in[4];
    const float* b_in  = (const float*)d_in[5];
    const float* gamma = (const float*)d_in[6];
    const float* beta  = (const float*)d_in[7];
    const float* Wh    = (const float*)d_in[8];
    const float* bh    = (const float*)d_in[9];
    float* out = (float*)d_out;

    char* w = (char*)d_ws;
    float*          vcolW  = (float*)w;                        // 800000 B
    unsigned short* WtW    = (unsigned short*)(w + 800000);    // 131072 B
    unsigned short* WgtpW  = (unsigned short*)(w + 931072);    // 98304 B
    float*          bias2W = (float*)(w + 1029376);            // 160 B

    k_prep<<<800, 256, 0, stream>>>(pi, pv, Win, Wh, gamma, beta, bh, vcolW, WtW, WgtpW, bias2W);
    k_fused<<<NBLK, 256, 0, stream>>>(feats, appd, WtW, WgtpW, vcolW, b_in, bias2W, out);
}

// Round 4
// 203.378 us; speedup vs baseline: 1.1488x; 1.1488x over previous
//
#include <hip/hip_runtime.h>
#include <hip/hip_bf16.h>

#define NROW 50000
#define DIN 128
#define DM 256
#define HH 4
#define NC 40
#define BHN 200000
#define NBLK 3125   // 50000 / 16 rows per wave

typedef float f32x4 __attribute__((ext_vector_type(4)));
typedef short bf16x8 __attribute__((ext_vector_type(8)));

__device__ __forceinline__ unsigned short f2bf(float x) {
    unsigned int u = __float_as_uint(x);
    u += 0x7fffu + ((u >> 16) & 1u);
    return (unsigned short)(u >> 16);
}

__device__ __forceinline__ unsigned int pk2(float lo, float hi) {
    __hip_bfloat162 h = __float22bfloat162_rn(make_float2(lo, hi));
    return *(unsigned int*)&h;
}

__device__ __forceinline__ float bf2f(unsigned short s) {
    return __uint_as_float(((unsigned int)s) << 16);
}

// -------- prep: all-parallel. blocks: [0,782) scatter, [782,798) Wt,
// [798,822) Wgtp, [822,862) bias2 --------
__global__ __launch_bounds__(256) void k_prep(const int* __restrict__ pi,
                                              const float* __restrict__ pv,
                                              const float* __restrict__ Win,
                                              const float* __restrict__ Wh,
                                              const float* __restrict__ gamma,
                                              const float* __restrict__ beta,
                                              const float* __restrict__ bh,
                                              float* __restrict__ vcol,
                                              unsigned short* __restrict__ Wt,
                                              unsigned short* __restrict__ Wgtp,
                                              float* __restrict__ bias2) {
    const int bid = blockIdx.x, tid = threadIdx.x;
    if (bid < 782) {                      // scatter: vcol[h][col] = v ; h = k/50000 (b_idx is repeat(arange))
        int k = bid * 256 + tid;
        if (k < BHN) {
            int b = (k >= 150000) ? 3 : (k >= 100000) ? 2 : (k >= 50000) ? 1 : 0;
            int col = pi[2 * BHN + k];
            vcol[b * NROW + col] = pv[k];
        }
    } else if (bid < 798) {               // Wt[n][k] = bf16(Win[k][n]); coalesced reads (n inner)
        int base = (bid - 782) * 4096;
        #pragma unroll
        for (int q = 0; q < 16; ++q) {
            int e = base + q * 256 + tid;
            int n = e & 255, k = e >> 8;
            Wt[n * DM + k] = f2bf(Win[k * DM + n]);
        }
    } else if (bid < 822) {               // Wgtp[c][d] = bf16(gamma[d]*Wh[d][c]), c in [0,48) zero-padded
        int base = (bid - 798) * 2048;
        #pragma unroll
        for (int q = 0; q < 8; ++q) {
            int e = base + q * 256 + tid;
            int d = e / 48, c = e - d * 48;
            Wgtp[c * 1024 + d] = (c < NC) ? f2bf(gamma[d] * Wh[d * NC + c]) : (unsigned short)0;
        }
    } else {                              // bias2[c] = bh[c] + sum_d beta[d]*Wh[d][c]
        __shared__ float red[256];
        int c = bid - 822;
        float s = 0.f;
        #pragma unroll
        for (int q = 0; q < 4; ++q) {
            int d = tid + 256 * q;
            s = fmaf(beta[d], Wh[d * NC + c], s);
        }
        red[tid] = s;
        __syncthreads();
        for (int st = 128; st > 0; st >>= 1) {
            if (tid < st) red[tid] += red[tid + st];
            __syncthreads();
        }
        if (tid == 0) bias2[c] = bh[c] + red[0];
    }
}

// -------- fused: one independent wave per 16 rows; no inter-wave cooperation --------
__global__ __launch_bounds__(64, 3) void k_fused(
    const float* __restrict__ feats, const float* __restrict__ appd,
    const unsigned short* __restrict__ Wt,   // [256 n][256 k] bf16
    const unsigned short* __restrict__ Wgtp, // [48 c][1024 d] bf16, gamma folded, zero-padded
    const float* __restrict__ vcol,          // [4][NROW]
    const float* __restrict__ b_in,          // [256]
    const float* __restrict__ bias2,         // [40]
    float* __restrict__ out)                 // [NROW][40]
{
    __shared__ __align__(16) unsigned short Gb[16 * 268];  // G bf16, row stride 268 shorts
    __shared__ __align__(16) float binS[256];
    __shared__ float rsS[16], nmS[16];

    const int tid = threadIdx.x;
    const int quad = tid >> 4;
    const int lr = tid & 15;
    const int j0 = blockIdx.x * 16;

    *(float4*)&binS[tid * 4] = *(const float4*)&b_in[tid * 4];

    // ---- phase 1: G[16 rows][256 cols] via MFMA, B-frags direct from L2 ----
    const int ar = j0 + lr;
    const f32x4 zero4 = {0.f, 0.f, 0.f, 0.f};
    f32x4 accG[16];
    #pragma unroll
    for (int t = 0; t < 16; ++t) accG[t] = zero4;

    #pragma unroll
    for (int kc = 0; kc < 8; ++kc) {
        const float* src = (kc < 4) ? feats : appd;
        const int ko = (kc & 3) * 32 + quad * 8;
        float4 x0 = *(const float4*)&src[(size_t)ar * DIN + ko];
        float4 x1 = *(const float4*)&src[(size_t)ar * DIN + ko + 4];
        union { unsigned int ui[4]; bf16x8 v; } u;
        u.ui[0] = pk2(x0.x, x0.y);
        u.ui[1] = pk2(x0.z, x0.w);
        u.ui[2] = pk2(x1.x, x1.y);
        u.ui[3] = pk2(x1.z, x1.w);
        #pragma unroll
        for (int t = 0; t < 16; ++t) {
            bf16x8 bf = *(const bf16x8*)&Wt[(size_t)(t * 16 + lr) * DM + kc * 32 + quad * 8];
            accG[t] = __builtin_amdgcn_mfma_f32_16x16x32_bf16(u.v, bf, accG[t], 0, 0, 0);
        }
    }

    // ---- phase 2: stats over 4 heads (rows quad*4+rg live in this quad group) ----
    __syncthreads();   // binS visible (single wave: just a waitcnt)
    float bt[16];
    #pragma unroll
    for (int t = 0; t < 16; ++t) bt[t] = binS[t * 16 + lr];
    float vh[HH][4];
    #pragma unroll
    for (int h = 0; h < HH; ++h)
        #pragma unroll
        for (int rg = 0; rg < 4; ++rg)
            vh[h][rg] = vcol[h * NROW + j0 + quad * 4 + rg];

    float s[4] = {0.f, 0.f, 0.f, 0.f}, ss[4] = {0.f, 0.f, 0.f, 0.f};
    #pragma unroll
    for (int t = 0; t < 16; ++t)
        #pragma unroll
        for (int rg = 0; rg < 4; ++rg) {
            float gg = accG[t][rg];
            // spill G to LDS (C-layout position) for the layout transform
            Gb[(quad * 4 + rg) * 268 + t * 16 + lr] = f2bf(gg);
            #pragma unroll
            for (int h = 0; h < HH; ++h) {
                float v = vh[h][rg];
                float y = v * fmaxf(fmaf(v, gg, bt[t]), 0.f);
                s[rg] += y;
                ss[rg] = fmaf(y, y, ss[rg]);
            }
        }
    #pragma unroll
    for (int m = 1; m <= 8; m <<= 1)
        #pragma unroll
        for (int rg = 0; rg < 4; ++rg) {
            s[rg] += __shfl_xor(s[rg], m);
            ss[rg] += __shfl_xor(ss[rg], m);
        }
    if (lr == 0) {
        #pragma unroll
        for (int rg = 0; rg < 4; ++rg) {
            float mm = s[rg] * (1.f / 1024.f);
            float var = ss[rg] * (1.f / 1024.f) - mm * mm;
            float r_ = rsqrtf(var + 1e-5f);
            rsS[quad * 4 + rg] = r_;
            nmS[quad * 4 + rg] = -mm * r_;
        }
    }
    __syncthreads();   // single wave: waitcnt only

    // ---- phase 3: per-lane row m=lr; z from G-frags (A-layout) per head; head MFMA ----
    float vm[HH];
    #pragma unroll
    for (int h = 0; h < HH; ++h) vm[h] = vcol[h * NROW + j0 + lr];
    const float rsm = rsS[lr], nmm = nmS[lr];

    f32x4 accO[3];
    #pragma unroll
    for (int t = 0; t < 3; ++t) accO[t] = zero4;

    #pragma unroll
    for (int kc = 0; kc < 8; ++kc) {
        bf16x8 gf = *(const bf16x8*)&Gb[lr * 268 + kc * 32 + quad * 8];
        float4 bA = *(const float4*)&binS[kc * 32 + quad * 8];
        float4 bB = *(const float4*)&binS[kc * 32 + quad * 8 + 4];
        float gg[8], bb[8];
        #pragma unroll
        for (int j = 0; j < 8; ++j) gg[j] = bf2f((unsigned short)gf[j]);
        bb[0] = bA.x; bb[1] = bA.y; bb[2] = bA.z; bb[3] = bA.w;
        bb[4] = bB.x; bb[5] = bB.y; bb[6] = bB.z; bb[7] = bB.w;
        #pragma unroll
        for (int h = 0; h < HH; ++h) {
            float z[8];
            #pragma unroll
            for (int j = 0; j < 8; ++j) {
                float y = vm[h] * fmaxf(fmaf(vm[h], gg[j], bb[j]), 0.f);
                z[j] = fmaf(y, rsm, nmm);
            }
            union { unsigned int ui[4]; bf16x8 v; } u;
            u.ui[0] = pk2(z[0], z[1]);
            u.ui[1] = pk2(z[2], z[3]);
            u.ui[2] = pk2(z[4], z[5]);
            u.ui[3] = pk2(z[6], z[7]);
            #pragma unroll
            for (int t = 0; t < 3; ++t) {
                bf16x8 bf = *(const bf16x8*)&Wgtp[(size_t)(t * 16 + lr) * 1024 + h * 256 + kc * 32 + quad * 8];
                accO[t] = __builtin_amdgcn_mfma_f32_16x16x32_bf16(u.v, bf, accO[t], 0, 0, 0);
            }
        }
    }

    // ---- store: C-layout rows quad*4+rg, cols t*16+lr ----
    float b2[3];
    #pragma unroll
    for (int t = 0; t < 3; ++t) {
        int c = t * 16 + lr;
        b2[t] = (c < NC) ? bias2[c] : 0.f;
    }
    #pragma unroll
    for (int t = 0; t < 3; ++t) {
        int c = t * 16 + lr;
        if (c < NC) {
            #pragma unroll
            for (int rg = 0; rg < 4; ++rg) {
                int row = j0 + quad * 4 + rg;
                out[(size_t)row * NC + c] = accO[t][rg] + b2[t];
            }
        }
    }
}

extern "C" void kernel_launch(void* const* d_in, const int* in_sizes, int n_in,
                              void* d_out, int out_size, void* d_ws, size_t ws_size,
                              hipStream_t stream) {
    const int*   pi    = (const int*)d_in[0];
    const float* pv    = (const float*)d_in[1];
    const float* feats = (const float*)d_in[2];
    const float* appd  = (const float*)d_in[3];
    const float* Win   = (const float*)d_in[4];
    const float* b_in  = (const float*)d_in[5];
    const float* gamma = (const float*)d_in[6];
    const float* beta  = (const float*)d_in[7];
    const float* Wh    = (const float*)d_in[8];
    const float* bh    = (const float*)d_in[9];
    float* out = (float*)d_out;

    char* w = (char*)d_ws;
    float*          vcolW  = (float*)w;                        // 800000 B
    unsigned short* WtW    = (unsigned short*)(w + 800000);    // 131072 B
    unsigned short* WgtpW  = (unsigned short*)(w + 931072);    // 98304 B
    float*          bias2W = (float*)(w + 1029376);            // 160 B

    k_prep<<<862, 256, 0, stream>>>(pi, pv, Win, Wh, gamma, beta, bh, vcolW, WtW, WgtpW, bias2W);
    k_fused<<<NBLK, 64, 0, stream>>>(feats, appd, WtW, WgtpW, vcolW, b_in, bias2W, out);
}

// Round 5
// 153.529 us; speedup vs baseline: 1.5219x; 1.3247x over previous
//
#include <hip/hip_runtime.h>
#include <hip/hip_bf16.h>

#define NROW 50000
#define DIN 128
#define DM 256
#define HH 4
#define NC 40
#define BHN 200000
#define NBLK 1563   // ceil(50000/32), 32 rows per wave

typedef float f32x4 __attribute__((ext_vector_type(4)));
typedef short bf16x8 __attribute__((ext_vector_type(8)));

__device__ __forceinline__ unsigned short f2bf(float x) {
    unsigned int u = __float_as_uint(x);
    u += 0x7fffu + ((u >> 16) & 1u);
    return (unsigned short)(u >> 16);
}

__device__ __forceinline__ unsigned int pk2(float lo, float hi) {
    __hip_bfloat162 h = __float22bfloat162_rn(make_float2(lo, hi));
    return *(unsigned int*)&h;
}

__device__ __forceinline__ float bf2f(unsigned short s) {
    return __uint_as_float(((unsigned int)s) << 16);
}

// -------- prep: blocks [0,782) scatter | [782,798) Wpk | [798,810) Wgpk | [810,850) bias2 --------
// Wpk  [kc][t][ln][8]: fragment-order packed bf16 of Win^T  (8*16*64*8 shorts)
// Wgpk [h][kc][t][ln][8]: fragment-order packed bf16 of gamma*Wh^T (4*8*3*64*8 shorts)
__global__ __launch_bounds__(256) void k_prep(const int* __restrict__ pi,
                                              const float* __restrict__ pv,
                                              const float* __restrict__ Win,
                                              const float* __restrict__ Wh,
                                              const float* __restrict__ gamma,
                                              const float* __restrict__ beta,
                                              const float* __restrict__ bh,
                                              float* __restrict__ vcol,
                                              unsigned short* __restrict__ Wpk,
                                              unsigned short* __restrict__ Wgpk,
                                              float* __restrict__ bias2) {
    const int bid = blockIdx.x, tid = threadIdx.x;
    if (bid < 782) {                      // scatter: vcol[h][col] = v ; b_idx = repeat(arange(4),50000)
        int k = bid * 256 + tid;
        if (k < BHN) {
            int b = (k >= 150000) ? 3 : (k >= 100000) ? 2 : (k >= 50000) ? 1 : 0;
            int col = pi[2 * BHN + k];
            vcol[b * NROW + col] = pv[k];
        }
    } else if (bid < 798) {               // Wpk: 16 blocks x 512 fragment-slots
        int base = (bid - 782) * 512;
        #pragma unroll
        for (int q = 0; q < 2; ++q) {
            int s = base + q * 256 + tid;            // s = (kc*16+t)*64 + ln
            int ln = s & 63;
            int t  = (s >> 6) & 15;
            int kc = s >> 10;
            int n  = t * 16 + (ln & 15);
            int kb = kc * 32 + ((ln >> 4) << 3);
            union { unsigned int ui[4]; uint4 v4; } u;
            #pragma unroll
            for (int jj = 0; jj < 4; ++jj)
                u.ui[jj] = pk2(Win[(kb + 2 * jj) * DM + n], Win[(kb + 2 * jj + 1) * DM + n]);
            *(uint4*)&Wpk[s * 8] = u.v4;
        }
    } else if (bid < 810) {               // Wgpk: 12 blocks x 512 slots
        int base = (bid - 798) * 512;
        #pragma unroll
        for (int q = 0; q < 2; ++q) {
            int s = base + q * 256 + tid;            // s = ((h*8+kc)*3+t)*64 + ln
            int ln = s & 63;
            int u6 = s >> 6;
            int t  = u6 % 3;
            int v6 = u6 / 3;
            int kc = v6 & 7;
            int h  = v6 >> 3;
            int c  = t * 16 + (ln & 15);
            int d0 = h * 256 + kc * 32 + ((ln >> 4) << 3);
            union { unsigned int ui[4]; uint4 v4; } u;
            if (c < NC) {
                #pragma unroll
                for (int jj = 0; jj < 4; ++jj)
                    u.ui[jj] = pk2(gamma[d0 + 2 * jj] * Wh[(d0 + 2 * jj) * NC + c],
                                   gamma[d0 + 2 * jj + 1] * Wh[(d0 + 2 * jj + 1) * NC + c]);
            } else {
                u.v4 = make_uint4(0u, 0u, 0u, 0u);
            }
            *(uint4*)&Wgpk[s * 8] = u.v4;
        }
    } else {                              // bias2[c] = bh[c] + sum_d beta[d]*Wh[d][c]
        __shared__ float red[256];
        int c = bid - 810;
        float sacc = 0.f;
        #pragma unroll
        for (int q = 0; q < 4; ++q) {
            int d = tid + 256 * q;
            sacc = fmaf(beta[d], Wh[d * NC + c], sacc);
        }
        red[tid] = sacc;
        __syncthreads();
        for (int st = 128; st > 0; st >>= 1) {
            if (tid < st) red[tid] += red[tid + st];
            __syncthreads();
        }
        if (tid == 0) bias2[c] = bh[c] + red[0];
    }
}

// -------- fused: one independent wave per 32 rows; coalesced packed weights --------
__global__ __launch_bounds__(64, 2) void k_fused(
    const float* __restrict__ feats, const float* __restrict__ appd,
    const unsigned short* __restrict__ Wpk,
    const unsigned short* __restrict__ Wgpk,
    const float* __restrict__ vcol,          // [4][NROW]
    const float* __restrict__ b_in,          // [256]
    const float* __restrict__ bias2,         // [40]
    float* __restrict__ out)                 // [NROW][40]
{
    __shared__ __align__(16) unsigned short Gb[32 * 264]; // G bf16, row stride 264 shorts (16B-aligned)
    __shared__ float rsS[32], nmS[32];

    const int tid = threadIdx.x;
    const int quad = tid >> 4;
    const int lr = tid & 15;
    const int j0 = blockIdx.x * 32;

    const int ar0 = min(j0 + lr, NROW - 1);
    const int ar1 = min(j0 + 16 + lr, NROW - 1);

    // ---- phase 1: G[32 rows][256 cols], B-frags coalesced from Wpk ----
    const f32x4 zero4 = {0.f, 0.f, 0.f, 0.f};
    f32x4 accG[2][16];
    #pragma unroll
    for (int rt = 0; rt < 2; ++rt)
        #pragma unroll
        for (int t = 0; t < 16; ++t) accG[rt][t] = zero4;

    #pragma unroll
    for (int kc = 0; kc < 8; ++kc) {
        const float* src = (kc < 4) ? feats : appd;
        const int ko = (kc & 3) * 32 + quad * 8;
        union { unsigned int ui[4]; bf16x8 v; } a0, a1;
        {
            float4 x0 = *(const float4*)&src[(size_t)ar0 * DIN + ko];
            float4 x1 = *(const float4*)&src[(size_t)ar0 * DIN + ko + 4];
            a0.ui[0] = pk2(x0.x, x0.y); a0.ui[1] = pk2(x0.z, x0.w);
            a0.ui[2] = pk2(x1.x, x1.y); a0.ui[3] = pk2(x1.z, x1.w);
            float4 y0 = *(const float4*)&src[(size_t)ar1 * DIN + ko];
            float4 y1 = *(const float4*)&src[(size_t)ar1 * DIN + ko + 4];
            a1.ui[0] = pk2(y0.x, y0.y); a1.ui[1] = pk2(y0.z, y0.w);
            a1.ui[2] = pk2(y1.x, y1.y); a1.ui[3] = pk2(y1.z, y1.w);
        }
        #pragma unroll
        for (int t = 0; t < 16; ++t) {
            bf16x8 bf = *(const bf16x8*)&Wpk[(size_t)(((kc * 16 + t) << 6) + tid) * 8];
            accG[0][t] = __builtin_amdgcn_mfma_f32_16x16x32_bf16(a0.v, bf, accG[0][t], 0, 0, 0);
            accG[1][t] = __builtin_amdgcn_mfma_f32_16x16x32_bf16(a1.v, bf, accG[1][t], 0, 0, 0);
        }
    }

    // ---- phase 2: spill G to LDS + LN stats ----
    float bt[16];
    #pragma unroll
    for (int t = 0; t < 16; ++t) bt[t] = b_in[t * 16 + lr];

    #pragma unroll
    for (int rt = 0; rt < 2; ++rt) {
        float vhh[HH][4];
        #pragma unroll
        for (int h = 0; h < HH; ++h)
            #pragma unroll
            for (int rg = 0; rg < 4; ++rg)
                vhh[h][rg] = vcol[h * NROW + min(j0 + rt * 16 + quad * 4 + rg, NROW - 1)];

        float s[4] = {0.f, 0.f, 0.f, 0.f}, ss[4] = {0.f, 0.f, 0.f, 0.f};
        #pragma unroll
        for (int t = 0; t < 16; ++t)
            #pragma unroll
            for (int rg = 0; rg < 4; ++rg) {
                float gg = accG[rt][t][rg];
                Gb[(rt * 16 + quad * 4 + rg) * 264 + t * 16 + lr] = f2bf(gg);
                #pragma unroll
                for (int h = 0; h < HH; ++h) {
                    float v = vhh[h][rg];
                    float y = v * fmaxf(fmaf(v, gg, bt[t]), 0.f);
                    s[rg] += y;
                    ss[rg] = fmaf(y, y, ss[rg]);
                }
            }
        #pragma unroll
        for (int m = 1; m <= 8; m <<= 1)
            #pragma unroll
            for (int rg = 0; rg < 4; ++rg) {
                s[rg] += __shfl_xor(s[rg], m);
                ss[rg] += __shfl_xor(ss[rg], m);
            }
        if (lr == 0) {
            #pragma unroll
            for (int rg = 0; rg < 4; ++rg) {
                float mm = s[rg] * (1.f / 1024.f);
                float var = ss[rg] * (1.f / 1024.f) - mm * mm;
                float r_ = rsqrtf(var + 1e-5f);
                rsS[rt * 16 + quad * 4 + rg] = r_;
                nmS[rt * 16 + quad * 4 + rg] = -mm * r_;
            }
        }
    }
    __syncthreads();

    // ---- phase 3: per-lane rows lr and 16+lr; z from LDS G-frags; coalesced Wgpk MFMAs ----
    float vm[HH][2];
    #pragma unroll
    for (int h = 0; h < HH; ++h) {
        vm[h][0] = vcol[h * NROW + min(j0 + lr, NROW - 1)];
        vm[h][1] = vcol[h * NROW + min(j0 + 16 + lr, NROW - 1)];
    }
    const float rs0 = rsS[lr], nm0 = nmS[lr];
    const float rs1 = rsS[16 + lr], nm1 = nmS[16 + lr];

    f32x4 accO[2][3];
    #pragma unroll
    for (int rt = 0; rt < 2; ++rt)
        #pragma unroll
        for (int t = 0; t < 3; ++t) accO[rt][t] = zero4;

    #pragma unroll
    for (int kc = 0; kc < 8; ++kc) {
        bf16x8 gf0 = *(const bf16x8*)&Gb[lr * 264 + kc * 32 + quad * 8];
        bf16x8 gf1 = *(const bf16x8*)&Gb[(16 + lr) * 264 + kc * 32 + quad * 8];
        float4 bA = *(const float4*)&b_in[kc * 32 + quad * 8];
        float4 bB = *(const float4*)&b_in[kc * 32 + quad * 8 + 4];
        float bb[8] = {bA.x, bA.y, bA.z, bA.w, bB.x, bB.y, bB.z, bB.w};
        float g0[8], g1[8];
        #pragma unroll
        for (int j = 0; j < 8; ++j) {
            g0[j] = bf2f((unsigned short)gf0[j]);
            g1[j] = bf2f((unsigned short)gf1[j]);
        }
        #pragma unroll
        for (int h = 0; h < HH; ++h) {
            union { unsigned int ui[4]; bf16x8 v; } u0, u1;
            #pragma unroll
            for (int jj = 0; jj < 4; ++jj) {
                float ya = vm[h][0] * fmaxf(fmaf(vm[h][0], g0[2 * jj], bb[2 * jj]), 0.f);
                float yb = vm[h][0] * fmaxf(fmaf(vm[h][0], g0[2 * jj + 1], bb[2 * jj + 1]), 0.f);
                u0.ui[jj] = pk2(fmaf(ya, rs0, nm0), fmaf(yb, rs0, nm0));
                float yc = vm[h][1] * fmaxf(fmaf(vm[h][1], g1[2 * jj], bb[2 * jj]), 0.f);
                float yd = vm[h][1] * fmaxf(fmaf(vm[h][1], g1[2 * jj + 1], bb[2 * jj + 1]), 0.f);
                u1.ui[jj] = pk2(fmaf(yc, rs1, nm1), fmaf(yd, rs1, nm1));
            }
            #pragma unroll
            for (int t = 0; t < 3; ++t) {
                bf16x8 wf = *(const bf16x8*)&Wgpk[(size_t)(((((h * 8 + kc) * 3 + t) << 6) + tid)) * 8];
                accO[0][t] = __builtin_amdgcn_mfma_f32_16x16x32_bf16(u0.v, wf, accO[0][t], 0, 0, 0);
                accO[1][t] = __builtin_amdgcn_mfma_f32_16x16x32_bf16(u1.v, wf, accO[1][t], 0, 0, 0);
            }
        }
    }

    // ---- store ----
    float b2[3];
    #pragma unroll
    for (int t = 0; t < 3; ++t) {
        int c = t * 16 + lr;
        b2[t] = (c < NC) ? bias2[c] : 0.f;
    }
    #pragma unroll
    for (int rt = 0; rt < 2; ++rt)
        #pragma unroll
        for (int t = 0; t < 3; ++t) {
            int c = t * 16 + lr;
            if (c < NC) {
                #pragma unroll
                for (int rg = 0; rg < 4; ++rg) {
                    int row = j0 + rt * 16 + quad * 4 + rg;
                    if (row < NROW)
                        out[(size_t)row * NC + c] = accO[rt][t][rg] + b2[t];
                }
            }
        }
}

extern "C" void kernel_launch(void* const* d_in, const int* in_sizes, int n_in,
                              void* d_out, int out_size, void* d_ws, size_t ws_size,
                              hipStream_t stream) {
    const int*   pi    = (const int*)d_in[0];
    const float* pv    = (const float*)d_in[1];
    const float* feats = (const float*)d_in[2];
    const float* appd  = (const float*)d_in[3];
    const float* Win   = (const float*)d_in[4];
    const float* b_in  = (const float*)d_in[5];
    const float* gamma = (const float*)d_in[6];
    const float* beta  = (const float*)d_in[7];
    const float* Wh    = (const float*)d_in[8];
    const float* bh    = (const float*)d_in[9];
    float* out = (float*)d_out;

    char* w = (char*)d_ws;
    float*          vcolW  = (float*)w;                        // 800000 B
    unsigned short* WpkW   = (unsigned short*)(w + 800000);    // 131072 B
    unsigned short* WgpkW  = (unsigned short*)(w + 931072);    // 98304 B
    float*          bias2W = (float*)(w + 1029376);            // 160 B

    k_prep<<<850, 256, 0, stream>>>(pi, pv, Win, Wh, gamma, beta, bh, vcolW, WpkW, WgpkW, bias2W);
    k_fused<<<NBLK, 64, 0, stream>>>(feats, appd, WpkW, WgpkW, vcolW, b_in, bias2W, out);
}